// Round 1
// baseline (464.656 us; speedup 1.0000x reference)
//
#include <hip/hip_runtime.h>
#include <hip/hip_bf16.h>

// RNN-T Joiner: logits[n,t,u,v] = tanh(enc@W_enc^T + b_enc  (+)  dec@W_dec^T + b_dec) @ W_out^T + b_out
// N=8 T=512 U=64 E=D=J=512 V=500.
// Stage 1: proj_gemm (bf16 MFMA, f32 out) -> ws:  enc_p [8*512,512], dec_p [8*64,512]
// Stage 2: joiner_main fused tanh+GEMM, A-tile computed on the fly, 128x256 tile, 8 waves.

typedef __attribute__((ext_vector_type(4))) float f32x4;
typedef __attribute__((ext_vector_type(8))) short s16x8;

static __device__ __forceinline__ unsigned short f2bf(float x) {
    union { float f; unsigned u; } v; v.f = x;
    return (unsigned short)((v.u + 0x7FFFu + ((v.u >> 16) & 1u)) >> 16);  // RNE
}

static __device__ __forceinline__ float fast_tanh(float x) {
    // tanh(x) = 1 - 2/(exp(2x)+1); robust at +-inf, ~1e-6 rel err << bf16 rounding
    float e = __expf(2.0f * x);
    return 1.0f - 2.0f / (e + 1.0f);
}

// ---------------- projection GEMM: C[m,j] = sum_k A[m,k] * W[j,k] + b[j] ----------------
// A [M,512] f32, W [512,512] f32, C [M,512] f32.  Tile 128x128, BK=64, 4 waves (2x2 of 64x64).
__global__ __launch_bounds__(256) void proj_gemm(
    const float* __restrict__ A, const float* __restrict__ W,
    const float* __restrict__ b, float* __restrict__ C)
{
    __shared__ unsigned short As[128 * 64];
    __shared__ unsigned short Bs[128 * 64];
    const int mt = blockIdx.x, jt = blockIdx.y;
    const int tid = threadIdx.x;
    const int lane = tid & 63, wid = tid >> 6;
    const int wm = wid >> 1, wn = wid & 1;

    f32x4 acc[4][4];
    const f32x4 zero = {0.f, 0.f, 0.f, 0.f};
    #pragma unroll
    for (int i = 0; i < 4; ++i)
        #pragma unroll
        for (int j = 0; j < 4; ++j) acc[i][j] = zero;

    const int c8 = (tid & 7) * 8;     // k offset within 64-wide tile
    const int rbase = tid >> 3;       // 0..31

    for (int kt = 0; kt < 8; ++kt) {
        __syncthreads();
        #pragma unroll
        for (int p = 0; p < 4; ++p) {
            int r = p * 32 + rbase;
            int byte = (r * 128 + c8 * 2) ^ ((r & 7) << 4);
            {
                const float* s = A + (size_t)(mt * 128 + r) * 512 + kt * 64 + c8;
                f32x4 v0 = *(const f32x4*)s, v1 = *(const f32x4*)(s + 4);
                s16x8 pk;
                pk[0] = (short)f2bf(v0[0]); pk[1] = (short)f2bf(v0[1]);
                pk[2] = (short)f2bf(v0[2]); pk[3] = (short)f2bf(v0[3]);
                pk[4] = (short)f2bf(v1[0]); pk[5] = (short)f2bf(v1[1]);
                pk[6] = (short)f2bf(v1[2]); pk[7] = (short)f2bf(v1[3]);
                *(s16x8*)((char*)As + byte) = pk;
            }
            {
                const float* s = W + (size_t)(jt * 128 + r) * 512 + kt * 64 + c8;
                f32x4 v0 = *(const f32x4*)s, v1 = *(const f32x4*)(s + 4);
                s16x8 pk;
                pk[0] = (short)f2bf(v0[0]); pk[1] = (short)f2bf(v0[1]);
                pk[2] = (short)f2bf(v0[2]); pk[3] = (short)f2bf(v0[3]);
                pk[4] = (short)f2bf(v1[0]); pk[5] = (short)f2bf(v1[1]);
                pk[6] = (short)f2bf(v1[2]); pk[7] = (short)f2bf(v1[3]);
                *(s16x8*)((char*)Bs + byte) = pk;
            }
        }
        __syncthreads();
        #pragma unroll
        for (int kk = 0; kk < 2; ++kk) {
            s16x8 af[4], bfr[4];
            #pragma unroll
            for (int mi = 0; mi < 4; ++mi) {
                int row = wm * 64 + mi * 16 + (lane & 15);
                int byte = (row * 128 + kk * 64 + ((lane >> 4) * 16)) ^ ((row & 7) << 4);
                af[mi] = *(const s16x8*)((const char*)As + byte);
            }
            #pragma unroll
            for (int ni = 0; ni < 4; ++ni) {
                int row = wn * 64 + ni * 16 + (lane & 15);
                int byte = (row * 128 + kk * 64 + ((lane >> 4) * 16)) ^ ((row & 7) << 4);
                bfr[ni] = *(const s16x8*)((const char*)Bs + byte);
            }
            #pragma unroll
            for (int mi = 0; mi < 4; ++mi)
                #pragma unroll
                for (int ni = 0; ni < 4; ++ni)
                    acc[mi][ni] = __builtin_amdgcn_mfma_f32_16x16x32_bf16(
                        af[mi], bfr[ni], acc[mi][ni], 0, 0, 0);
        }
    }

    #pragma unroll
    for (int ni = 0; ni < 4; ++ni) {
        int col = jt * 128 + wn * 64 + ni * 16 + (lane & 15);
        float bias = b[col];
        #pragma unroll
        for (int mi = 0; mi < 4; ++mi) {
            int row0 = mt * 128 + wm * 64 + mi * 16 + ((lane >> 4) << 2);
            #pragma unroll
            for (int j = 0; j < 4; ++j)
                C[(size_t)(row0 + j) * 512 + col] = acc[mi][ni][j] + bias;
        }
    }
}

// ---------------- fused main GEMM ----------------
// per n: C[m=t*64+u, v] = sum_j tanh(enc[n,t,j] + dec[n,u,j]) * Wout[v,j] + bout[v]
// tile: BM=128 (2 t-rows x 64 u), BN=256 (2 v-tiles over 500), BK=64, 8 waves (2x4 of 64x64)
__global__ __launch_bounds__(512) void joiner_main(
    const float* __restrict__ enc, const float* __restrict__ dec,
    const float* __restrict__ Wout, const float* __restrict__ bout,
    float* __restrict__ out)
{
    __shared__ unsigned short As[128 * 64];   // 16 KB
    __shared__ unsigned short Bs[256 * 64];   // 32 KB
    const int bid = blockIdx.x;
    const int vt = bid & 1;            // 2 vocab tiles
    const int mt = (bid >> 1) & 255;   // 256 m-tiles
    const int n  = bid >> 9;           // 8 batch
    const int tid = threadIdx.x, lane = tid & 63, wid = tid >> 6;
    const int wm = wid >> 2, wn = wid & 3;

    const float* encN = enc + (size_t)n * (512 * 512);
    const float* decN = dec + (size_t)n * (64 * 512);

    f32x4 acc[4][4];
    const f32x4 zero = {0.f, 0.f, 0.f, 0.f};
    #pragma unroll
    for (int i = 0; i < 4; ++i)
        #pragma unroll
        for (int j = 0; j < 4; ++j) acc[i][j] = zero;

    const int c8 = (tid & 7) * 8;
    const int rbase = tid >> 3;        // 0..63

    for (int kt = 0; kt < 8; ++kt) {
        __syncthreads();
        // ---- stage A: activations 128 rows x 64 k (2 passes of 64 rows) ----
        #pragma unroll
        for (int p = 0; p < 2; ++p) {
            int r = p * 64 + rbase;
            int t = r >> 6, u = r & 63;
            const float* es = encN + (size_t)(mt * 2 + t) * 512 + kt * 64 + c8;
            const float* dsrc = decN + (size_t)u * 512 + kt * 64 + c8;
            f32x4 e0 = *(const f32x4*)es, e1 = *(const f32x4*)(es + 4);
            f32x4 d0 = *(const f32x4*)dsrc, d1 = *(const f32x4*)(dsrc + 4);
            s16x8 pk;
            pk[0] = (short)f2bf(fast_tanh(e0[0] + d0[0]));
            pk[1] = (short)f2bf(fast_tanh(e0[1] + d0[1]));
            pk[2] = (short)f2bf(fast_tanh(e0[2] + d0[2]));
            pk[3] = (short)f2bf(fast_tanh(e0[3] + d0[3]));
            pk[4] = (short)f2bf(fast_tanh(e1[0] + d1[0]));
            pk[5] = (short)f2bf(fast_tanh(e1[1] + d1[1]));
            pk[6] = (short)f2bf(fast_tanh(e1[2] + d1[2]));
            pk[7] = (short)f2bf(fast_tanh(e1[3] + d1[3]));
            int byte = (r * 128 + c8 * 2) ^ ((r & 7) << 4);
            *(s16x8*)((char*)As + byte) = pk;
        }
        // ---- stage B: W_out 256 rows x 64 k (4 passes of 64 rows), pad v>=500 with 0 ----
        #pragma unroll
        for (int p = 0; p < 4; ++p) {
            int r = p * 64 + rbase;
            int v = vt * 256 + r;
            f32x4 w0 = zero, w1 = zero;
            if (v < 500) {
                const float* s = Wout + (size_t)v * 512 + kt * 64 + c8;
                w0 = *(const f32x4*)s; w1 = *(const f32x4*)(s + 4);
            }
            s16x8 pk;
            pk[0] = (short)f2bf(w0[0]); pk[1] = (short)f2bf(w0[1]);
            pk[2] = (short)f2bf(w0[2]); pk[3] = (short)f2bf(w0[3]);
            pk[4] = (short)f2bf(w1[0]); pk[5] = (short)f2bf(w1[1]);
            pk[6] = (short)f2bf(w1[2]); pk[7] = (short)f2bf(w1[3]);
            int byte = (r * 128 + c8 * 2) ^ ((r & 7) << 4);
            *(s16x8*)((char*)Bs + byte) = pk;
        }
        __syncthreads();
        // ---- MFMA: 2 k-slices x 4x4 fragments ----
        #pragma unroll
        for (int kk = 0; kk < 2; ++kk) {
            s16x8 af[4], bfr[4];
            #pragma unroll
            for (int mi = 0; mi < 4; ++mi) {
                int row = wm * 64 + mi * 16 + (lane & 15);
                int byte = (row * 128 + kk * 64 + ((lane >> 4) * 16)) ^ ((row & 7) << 4);
                af[mi] = *(const s16x8*)((const char*)As + byte);
            }
            #pragma unroll
            for (int ni = 0; ni < 4; ++ni) {
                int row = wn * 64 + ni * 16 + (lane & 15);
                int byte = (row * 128 + kk * 64 + ((lane >> 4) * 16)) ^ ((row & 7) << 4);
                bfr[ni] = *(const s16x8*)((const char*)Bs + byte);
            }
            #pragma unroll
            for (int mi = 0; mi < 4; ++mi)
                #pragma unroll
                for (int ni = 0; ni < 4; ++ni)
                    acc[mi][ni] = __builtin_amdgcn_mfma_f32_16x16x32_bf16(
                        af[mi], bfr[ni], acc[mi][ni], 0, 0, 0);
        }
    }

    // ---- epilogue: out[n, mt*128 + r, v] = acc + bout[v], V=500 row stride ----
    const size_t base = ((size_t)n * 32768 + (size_t)mt * 128) * 500;
    #pragma unroll
    for (int ni = 0; ni < 4; ++ni) {
        int v = vt * 256 + wn * 64 + ni * 16 + (lane & 15);
        if (v < 500) {
            float bias = bout[v];
            #pragma unroll
            for (int mi = 0; mi < 4; ++mi) {
                int r0 = wm * 64 + mi * 16 + ((lane >> 4) << 2);
                #pragma unroll
                for (int j = 0; j < 4; ++j)
                    out[base + (size_t)(r0 + j) * 500 + v] = acc[mi][ni][j] + bias;
            }
        }
    }
}

extern "C" void kernel_launch(void* const* d_in, const int* in_sizes, int n_in,
                              void* d_out, int out_size, void* d_ws, size_t ws_size,
                              hipStream_t stream) {
    const float* encoder_out = (const float*)d_in[0];  // [8,512,512]
    const float* decoder_out = (const float*)d_in[1];  // [8,64,512]
    const float* W_enc = (const float*)d_in[2];        // [512,512]
    const float* b_enc = (const float*)d_in[3];        // [512]
    const float* W_dec = (const float*)d_in[4];        // [512,512]
    const float* b_dec = (const float*)d_in[5];        // [512]
    const float* W_out = (const float*)d_in[6];        // [500,512]
    const float* b_out = (const float*)d_in[7];        // [500]
    float* out = (float*)d_out;                        // [8,512,64,500]

    float* enc_p = (float*)d_ws;                       // 8*512*512 f32 = 8 MB
    float* dec_p = enc_p + (size_t)8 * 512 * 512;      // 8*64*512 f32 = 1 MB

    // encoder projection: M = 8*512 = 4096
    proj_gemm<<<dim3(32, 4), 256, 0, stream>>>(encoder_out, W_enc, b_enc, enc_p);
    // decoder projection: M = 8*64 = 512
    proj_gemm<<<dim3(4, 4), 256, 0, stream>>>(decoder_out, W_dec, b_dec, dec_p);
    // fused tanh + vocab GEMM: 8 n * 256 m-tiles * 2 v-tiles
    joiner_main<<<dim3(4096), 512, 0, stream>>>(enc_p, dec_p, W_out, b_out, out);
}